// Round 1
// baseline (1066.391 us; speedup 1.0000x reference)
//
#include <hip/hip_runtime.h>
#include <hip/hip_bf16.h>

#define T_SEQ 2048
#define D_MODEL 2048
#define NH 16
#define NKVH 4
#define HD 128

typedef __attribute__((ext_vector_type(8))) short bf16x8;
typedef __attribute__((ext_vector_type(4))) float f32x4;

static __device__ __forceinline__ short f32_to_bf16(float f) {
    unsigned u = __float_as_uint(f);
    unsigned r = 0x7fffu + ((u >> 16) & 1u);
    u += r;
    return (short)(u >> 16);
}

// ---------------------------------------------------------------------------
// GEMM: C[M,N] = act(A[M,K] @ B[K,N] + bias), fp32 in/out, bf16 MFMA inside.
// 128x128 tile, 256 threads (4 waves, 2x2 of 64x64), BK=32.
// All of M,K multiples of 128; N multiple of 128. No bounds checks.
// ---------------------------------------------------------------------------
__global__ __launch_bounds__(256) void gemm_bf16_kernel(
    const float* __restrict__ A, const float* __restrict__ B,
    float* __restrict__ C, int M, int N, int K,
    const float* __restrict__ bias, int act)
{
    __shared__ short Alds[128][40];   // [m][k], stride 40 (80B, 16B-aligned rows)
    __shared__ short Blds[128][40];   // B^T: [n][k]

    const int tid = threadIdx.x;
    const int wave = tid >> 6;
    const int lane = tid & 63;
    const int l16 = lane & 15;
    const int quad = lane >> 4;
    const int wm = (wave >> 1) * 64;
    const int wn = (wave & 1) * 64;

    const int m0 = blockIdx.y * 128;
    const int n0 = blockIdx.x * 128;

    f32x4 acc[4][4] = {};

    for (int k0 = 0; k0 < K; k0 += 32) {
        // stage A tile 128x32 (fp32 -> bf16)
        #pragma unroll
        for (int p = 0; p < 4; ++p) {
            int row = (tid >> 3) + p * 32;
            int col = (tid & 7) * 4;
            float4 v = *(const float4*)&A[(size_t)(m0 + row) * K + k0 + col];
            Alds[row][col + 0] = f32_to_bf16(v.x);
            Alds[row][col + 1] = f32_to_bf16(v.y);
            Alds[row][col + 2] = f32_to_bf16(v.z);
            Alds[row][col + 3] = f32_to_bf16(v.w);
        }
        // stage B tile 32x128 transposed -> Blds[n][k]
        #pragma unroll
        for (int p = 0; p < 4; ++p) {
            int krow = (tid >> 5) + p * 8;
            int col = (tid & 31) * 4;
            float4 v = *(const float4*)&B[(size_t)(k0 + krow) * N + n0 + col];
            Blds[col + 0][krow] = f32_to_bf16(v.x);
            Blds[col + 1][krow] = f32_to_bf16(v.y);
            Blds[col + 2][krow] = f32_to_bf16(v.z);
            Blds[col + 3][krow] = f32_to_bf16(v.w);
        }
        __syncthreads();

        bf16x8 a[4], b[4];
        #pragma unroll
        for (int i = 0; i < 4; ++i)
            a[i] = *(const bf16x8*)&Alds[wm + i * 16 + l16][quad * 8];
        #pragma unroll
        for (int i = 0; i < 4; ++i)
            b[i] = *(const bf16x8*)&Blds[wn + i * 16 + l16][quad * 8];
        #pragma unroll
        for (int mi = 0; mi < 4; ++mi)
            #pragma unroll
            for (int ni = 0; ni < 4; ++ni)
                acc[mi][ni] = __builtin_amdgcn_mfma_f32_16x16x32_bf16(
                    a[mi], b[ni], acc[mi][ni], 0, 0, 0);
        __syncthreads();
    }

    #pragma unroll
    for (int mi = 0; mi < 4; ++mi) {
        #pragma unroll
        for (int ni = 0; ni < 4; ++ni) {
            int col = n0 + wn + ni * 16 + l16;
            float bv = bias ? bias[col] : 0.0f;
            #pragma unroll
            for (int r = 0; r < 4; ++r) {
                int row = m0 + wm + mi * 16 + quad * 4 + r;
                float x = acc[mi][ni][r] + bv;
                if (act == 1) x = x / (1.0f + __expf(-x));  // silu
                C[(size_t)row * N + col] = x;
            }
        }
    }
}

// ---------------------------------------------------------------------------
// Causal prefix EMA, windowed (beta^256 ~ 2e-12 => fp32-exact).
// grid (T/128, D/256), block 256. Thread = one channel d, one chunk of 128 t.
// ---------------------------------------------------------------------------
__global__ void ema_kernel(const float* __restrict__ hs, float* __restrict__ l2)
{
    int d = blockIdx.y * 256 + threadIdx.x;
    int t0 = blockIdx.x * 128;
    int ts = t0 - 256; if (ts < 0) ts = 0;
    float m = 0.0f;
    for (int t = ts; t < t0 + 128; ++t) {
        m = 0.9f * m + 0.1f * hs[(size_t)t * D_MODEL + d];
        if (t >= t0) l2[(size_t)t * D_MODEL + d] = m;
    }
}

// ---------------------------------------------------------------------------
// Router head: logits = h[t,:]@Wr2 + br2 ; lam = softmax (2-way). 1 wave/row.
// ---------------------------------------------------------------------------
__global__ __launch_bounds__(64) void lam_kernel(
    const float* __restrict__ h, const float* __restrict__ Wr2,
    const float* __restrict__ br2, float* __restrict__ lam)
{
    int t = blockIdx.x;
    int lane = threadIdx.x;
    float z0 = 0.0f, z1 = 0.0f;
    for (int i = lane; i < 1024; i += 64) {
        float hv = h[(size_t)t * 1024 + i];
        z0 += hv * Wr2[i * 2 + 0];
        z1 += hv * Wr2[i * 2 + 1];
    }
    #pragma unroll
    for (int off = 1; off < 64; off <<= 1) {
        z0 += __shfl_xor(z0, off);
        z1 += __shfl_xor(z1, off);
    }
    if (lane == 0) {
        z0 += br2[0]; z1 += br2[1];
        float mx = fmaxf(z0, z1);
        float e0 = expf(z0 - mx), e1 = expf(z1 - mx);
        float inv = 1.0f / (e0 + e1);
        lam[t * 2 + 0] = e0 * inv;
        lam[t * 2 + 1] = e1 * inv;
    }
}

// fused = lam0*hs + lam1*l2  (float4 elementwise over T*D/4)
__global__ void fuse_kernel(const float* __restrict__ hs, const float* __restrict__ l2,
                            const float* __restrict__ lam, float* __restrict__ fused)
{
    int idx = blockIdx.x * blockDim.x + threadIdx.x;   // T*D/4
    int t = idx >> 9;                                  // 512 float4 per row
    float a0 = lam[t * 2 + 0], a1 = lam[t * 2 + 1];
    float4 a = ((const float4*)hs)[idx];
    float4 b = ((const float4*)l2)[idx];
    float4 o;
    o.x = a0 * a.x + a1 * b.x;
    o.y = a0 * a.y + a1 * b.y;
    o.z = a0 * a.z + a1 * b.z;
    o.w = a0 * a.w + a1 * b.w;
    ((float4*)fused)[idx] = o;
}

// RoPE on q, repack (T, H*HD) fp32 -> (H, T, HD) bf16. One thread per element.
__global__ void rope_q_kernel(const float* __restrict__ q, short* __restrict__ qr)
{
    int idx = blockIdx.x * blockDim.x + threadIdx.x;   // T*NH*HD = 4M
    int d = idx & 127;
    int h = (idx >> 7) & 15;
    int t = idx >> 11;
    int i = d & 63;
    // inv_freq = 10000^(-i/64) = exp(-i * ln(10000)/64)
    float freq = (float)t * expf(-(float)i * 0.14391156831212787f);
    float s, c;
    sincosf(freq, &s, &c);
    float x = q[(size_t)t * D_MODEL + h * HD + d];
    float xr = (d < 64) ? -q[(size_t)t * D_MODEL + h * HD + d + 64]
                        :  q[(size_t)t * D_MODEL + h * HD + d - 64];
    qr[((size_t)h * T_SEQ + t) * HD + d] = f32_to_bf16(x * c + xr * s);
}

// RoPE on k + pack v: (T, KVH*HD) fp32 -> (KVH, T, HD) bf16
__global__ void kv_pack_kernel(const float* __restrict__ k, const float* __restrict__ v,
                               short* __restrict__ kr, short* __restrict__ vr)
{
    int idx = blockIdx.x * blockDim.x + threadIdx.x;   // T*NKVH*HD = 1M
    int d = idx & 127;
    int kh = (idx >> 7) & 3;
    int t = idx >> 9;
    int i = d & 63;
    float freq = (float)t * expf(-(float)i * 0.14391156831212787f);
    float s, c;
    sincosf(freq, &s, &c);
    float x = k[(size_t)t * 512 + kh * HD + d];
    float xr = (d < 64) ? -k[(size_t)t * 512 + kh * HD + d + 64]
                        :  k[(size_t)t * 512 + kh * HD + d - 64];
    size_t dst = ((size_t)kh * T_SEQ + t) * HD + d;
    kr[dst] = f32_to_bf16(x * c + xr * s);
    vr[dst] = f32_to_bf16(v[(size_t)t * 512 + kh * HD + d]);
}

// ---------------------------------------------------------------------------
// Causal flash attention. Block = (qt, h): 64 q-rows, 4 waves x 16 rows.
// KV tiles of 32. GQA: kv head = h/4. Out fp32 (T, H*HD).
// ---------------------------------------------------------------------------
__global__ __launch_bounds__(256) void attn_kernel(
    const short* __restrict__ Qr, const short* __restrict__ Kr,
    const short* __restrict__ Vr, float* __restrict__ Out)
{
    const int qt = blockIdx.x;
    const int h = blockIdx.y;
    const int kvh = h >> 2;
    const int tid = threadIdx.x;
    const int wave = tid >> 6, lane = tid & 63;
    const int l16 = lane & 15, quad = lane >> 4;

    __shared__ short Klds[32][136];    // [kv][hd], stride 136 (272B rows)
    __shared__ short Vtlds[128][40];   // V^T: [hd][kv]
    __shared__ short Plds[4][16][40];  // per-wave P: [qrow][kv]

    const int qbase = qt * 64 + wave * 16;

    bf16x8 qf[4];
    {
        const short* qrow = Qr + ((size_t)h * T_SEQ + qbase + l16) * HD;
        #pragma unroll
        for (int kc = 0; kc < 4; ++kc)
            qf[kc] = *(const bf16x8*)&qrow[kc * 32 + quad * 8];
    }

    f32x4 o[8] = {};
    float m_i[4], l_i[4];
    #pragma unroll
    for (int r = 0; r < 4; ++r) { m_i[r] = -1e30f; l_i[r] = 0.0f; }

    const float scale = 0.08838834764831845f;  // 1/sqrt(128)
    const int kv_end = qt * 64 + 64;

    for (int kv0 = 0; kv0 < kv_end; kv0 += 32) {
        // stage K tile 32x128 row-major
        {
            int r = tid >> 4;
            int c8 = (tid & 15) * 8;
            const short* ksrc = Kr + ((size_t)kvh * T_SEQ + kv0) * HD;
            #pragma unroll
            for (int p = 0; p < 2; ++p) {
                uint4 vv = *(const uint4*)&ksrc[(size_t)(r + p * 16) * HD + c8];
                *(uint4*)&Klds[r + p * 16][c8] = vv;
            }
            // stage V transposed
            int cc = (tid >> 4) * 8;
            int vrow = tid & 15;
            const short* vsrc = Vr + ((size_t)kvh * T_SEQ + kv0) * HD;
            #pragma unroll
            for (int p = 0; p < 2; ++p) {
                int row = vrow + p * 16;
                uint4 vv = *(const uint4*)&vsrc[(size_t)row * HD + cc];
                const short* e = (const short*)&vv;
                #pragma unroll
                for (int j = 0; j < 8; ++j)
                    Vtlds[cc + j][row] = e[j];
            }
        }
        __syncthreads();

        bool active = (kv0 <= qbase + 15);
        if (active) {
            // S = Q K^T  (two 16-col kv subtiles)
            f32x4 s[2] = {};
            #pragma unroll
            for (int ni = 0; ni < 2; ++ni) {
                #pragma unroll
                for (int kc = 0; kc < 4; ++kc) {
                    bf16x8 b = *(const bf16x8*)&Klds[ni * 16 + l16][kc * 32 + quad * 8];
                    s[ni] = __builtin_amdgcn_mfma_f32_16x16x32_bf16(qf[kc], b, s[ni], 0, 0, 0);
                }
            }
            float alpha[4], p0[4], p1[4];
            #pragma unroll
            for (int r = 0; r < 4; ++r) {
                int qg = qbase + quad * 4 + r;
                float s0 = s[0][r] * scale;
                float s1 = s[1][r] * scale;
                if (kv0 + l16 > qg)      s0 = -1e30f;
                if (kv0 + 16 + l16 > qg) s1 = -1e30f;
                float vm = fmaxf(s0, s1);
                #pragma unroll
                for (int off = 1; off < 16; off <<= 1)
                    vm = fmaxf(vm, __shfl_xor(vm, off));
                float mn = fmaxf(m_i[r], vm);
                alpha[r] = __expf(m_i[r] - mn);
                p0[r] = __expf(s0 - mn);
                p1[r] = __expf(s1 - mn);
                float rs = p0[r] + p1[r];
                #pragma unroll
                for (int off = 1; off < 16; off <<= 1)
                    rs += __shfl_xor(rs, off);
                l_i[r] = alpha[r] * l_i[r] + rs;
                m_i[r] = mn;
            }
            // P (C-layout) -> LDS -> A-layout
            #pragma unroll
            for (int r = 0; r < 4; ++r) {
                Plds[wave][quad * 4 + r][l16]      = f32_to_bf16(p0[r]);
                Plds[wave][quad * 4 + r][16 + l16] = f32_to_bf16(p1[r]);
            }
            asm volatile("s_waitcnt lgkmcnt(0)" ::: "memory");
            #pragma unroll
            for (int dsub = 0; dsub < 8; ++dsub)
                #pragma unroll
                for (int r = 0; r < 4; ++r)
                    o[dsub][r] *= alpha[r];
            bf16x8 pa = *(const bf16x8*)&Plds[wave][l16][quad * 8];
            #pragma unroll
            for (int dsub = 0; dsub < 8; ++dsub) {
                bf16x8 b = *(const bf16x8*)&Vtlds[dsub * 16 + l16][quad * 8];
                o[dsub] = __builtin_amdgcn_mfma_f32_16x16x32_bf16(pa, b, o[dsub], 0, 0, 0);
            }
        }
        __syncthreads();
    }

    #pragma unroll
    for (int dsub = 0; dsub < 8; ++dsub) {
        #pragma unroll
        for (int r = 0; r < 4; ++r) {
            int row = qbase + quad * 4 + r;
            Out[(size_t)row * D_MODEL + h * HD + dsub * 16 + l16] = o[dsub][r] / l_i[r];
        }
    }
}

// ---------------------------------------------------------------------------
extern "C" void kernel_launch(void* const* d_in, const int* in_sizes, int n_in,
                              void* d_out, int out_size, void* d_ws, size_t ws_size,
                              hipStream_t stream)
{
    const float* hs  = (const float*)d_in[0];
    const float* Wq  = (const float*)d_in[1];
    const float* Wk  = (const float*)d_in[2];
    const float* Wv  = (const float*)d_in[3];
    const float* Wo  = (const float*)d_in[4];
    const float* Wr1 = (const float*)d_in[5];
    const float* br1 = (const float*)d_in[6];
    const float* Wr2 = (const float*)d_in[7];
    const float* br2 = (const float*)d_in[8];
    float* out = (float*)d_out;

    char* w = (char*)d_ws;
    const size_t MB = 1u << 20;
    float* q_f    = (float*)(w + 0 * MB);    // 16 MB (T x 2048)
    float* l2_f   = (float*)(w + 16 * MB);   // 16 MB
    float* fused_f= (float*)(w + 32 * MB);   // 16 MB
    float* h_f    = (float*)(w + 48 * MB);   // 8 MB  (T x 1024)
    float* attn_f = (float*)(w + 56 * MB);   // 16 MB (T x 2048)
    float* k_f    = (float*)(w + 72 * MB);   // 4 MB  (T x 512)
    float* v_f    = (float*)(w + 76 * MB);   // 4 MB
    float* lam_f  = (float*)(w + 80 * MB);   // 16 KB
    short* qr     = (short*)(w + 81 * MB);   // 8 MB bf16 (H,T,HD)
    short* kr     = (short*)(w + 89 * MB);   // 2 MB
    short* vr     = (short*)(w + 91 * MB);   // 2 MB; total 93 MB

    // l2 = causal EMA of hs
    ema_kernel<<<dim3(T_SEQ / 128, D_MODEL / 256), 256, 0, stream>>>(hs, l2_f);
    // q = hs @ Wq
    gemm_bf16_kernel<<<dim3(2048 / 128, 2048 / 128), 256, 0, stream>>>(
        hs, Wq, q_f, 2048, 2048, 2048, nullptr, 0);
    // h = silu(q @ Wr1 + br1)
    gemm_bf16_kernel<<<dim3(1024 / 128, 2048 / 128), 256, 0, stream>>>(
        q_f, Wr1, h_f, 2048, 1024, 2048, br1, 1);
    // lam = softmax(h @ Wr2 + br2)
    lam_kernel<<<T_SEQ, 64, 0, stream>>>(h_f, Wr2, br2, lam_f);
    // fused = lam0*hs + lam1*l2
    fuse_kernel<<<(T_SEQ * D_MODEL / 4) / 256, 256, 0, stream>>>(hs, l2_f, lam_f, fused_f);
    // k, v projections
    gemm_bf16_kernel<<<dim3(512 / 128, 2048 / 128), 256, 0, stream>>>(
        fused_f, Wk, k_f, 2048, 512, 2048, nullptr, 0);
    gemm_bf16_kernel<<<dim3(512 / 128, 2048 / 128), 256, 0, stream>>>(
        fused_f, Wv, v_f, 2048, 512, 2048, nullptr, 0);
    // RoPE + head-major bf16 repack
    rope_q_kernel<<<(T_SEQ * NH * HD) / 256, 256, 0, stream>>>(q_f, qr);
    kv_pack_kernel<<<(T_SEQ * NKVH * HD) / 256, 256, 0, stream>>>(k_f, v_f, kr, vr);
    // causal flash attention
    attn_kernel<<<dim3(T_SEQ / 64, NH), 256, 0, stream>>>(qr, kr, vr, attn_f);
    // out = attn @ Wo
    gemm_bf16_kernel<<<dim3(2048 / 128, 2048 / 128), 256, 0, stream>>>(
        attn_f, Wo, out, 2048, 2048, 2048, nullptr, 0);
}

// Round 2
// 471.969 us; speedup vs baseline: 2.2594x; 2.2594x over previous
//
#include <hip/hip_runtime.h>
#include <hip/hip_bf16.h>

#define T_SEQ 2048
#define D_MODEL 2048
#define NH 16
#define NKVH 4
#define HD 128

typedef __attribute__((ext_vector_type(8))) short bf16x8;
typedef __attribute__((ext_vector_type(4))) float f32x4;

static __device__ __forceinline__ short f32_to_bf16(float f) {
    unsigned u = __float_as_uint(f);
    u += 0x7fffu + ((u >> 16) & 1u);
    return (short)(u >> 16);
}
static __device__ __forceinline__ float bf16_to_f32(short s) {
    return __uint_as_float(((unsigned)(unsigned short)s) << 16);
}
static __device__ __forceinline__ void gl_to_lds16(const void* g, void* l) {
    __builtin_amdgcn_global_load_lds(
        (const __attribute__((address_space(1))) unsigned int*)g,
        (__attribute__((address_space(3))) unsigned int*)l, 16, 0, 0);
}

// ---------------------------------------------------------------------------
// m97-style GEMM: A bf16 (M x K), Bt bf16 (N x K), BK=32, BN=128.
// BM=128: 4 waves 2x2 of 64x64 (acc 4x4). BM=64: 4 waves 64x32 (acc 4x2).
// Stages via global_load_lds width 16 (LDS layout = linear, required by HW).
// ---------------------------------------------------------------------------
template<int BM>
__global__ __launch_bounds__(256) void gemm_bt_kernel(
    const short* __restrict__ A, const short* __restrict__ Bt,
    float* __restrict__ Cf, short* __restrict__ Cb,
    int M, int N, int K, const float* __restrict__ bias, int act)
{
    constexpr int NI = (BM == 128) ? 4 : 2;
    __shared__ short Alds[BM * 32];
    __shared__ short Blds[128 * 32];

    const int tid = threadIdx.x;
    const int wave = tid >> 6, lane = tid & 63;
    const int l16 = lane & 15, quad = lane >> 4;
    const int wm = (BM == 128) ? (wave >> 1) * 64 : 0;
    const int wn = (BM == 128) ? (wave & 1) * 64 : wave * 32;
    const int m0 = blockIdx.y * BM, n0 = blockIdx.x * 128;

    f32x4 acc[4][NI] = {};

    for (int k0 = 0; k0 < K; k0 += 32) {
        if (BM == 128) {
            #pragma unroll
            for (int p = 0; p < 2; ++p) {
                int li = p * 256 + tid;
                gl_to_lds16(A + (size_t)(m0 + (li >> 2)) * K + k0 + (li & 3) * 8,
                            Alds + (size_t)(p * 256 + wave * 64) * 8);
            }
        } else {
            gl_to_lds16(A + (size_t)(m0 + (tid >> 2)) * K + k0 + (tid & 3) * 8,
                        Alds + (size_t)(wave * 64) * 8);
        }
        #pragma unroll
        for (int p = 0; p < 2; ++p) {
            int li = p * 256 + tid;
            gl_to_lds16(Bt + (size_t)(n0 + (li >> 2)) * K + k0 + (li & 3) * 8,
                        Blds + (size_t)(p * 256 + wave * 64) * 8);
        }
        __syncthreads();

        bf16x8 a[4], b[NI];
        #pragma unroll
        for (int i = 0; i < 4; ++i)
            a[i] = *(const bf16x8*)&Alds[(wm + i * 16 + l16) * 32 + quad * 8];
        #pragma unroll
        for (int i = 0; i < NI; ++i)
            b[i] = *(const bf16x8*)&Blds[(wn + i * 16 + l16) * 32 + quad * 8];
        #pragma unroll
        for (int mi = 0; mi < 4; ++mi)
            #pragma unroll
            for (int ni = 0; ni < NI; ++ni)
                acc[mi][ni] = __builtin_amdgcn_mfma_f32_16x16x32_bf16(
                    a[mi], b[ni], acc[mi][ni], 0, 0, 0);
        __syncthreads();
    }

    #pragma unroll
    for (int mi = 0; mi < 4; ++mi) {
        #pragma unroll
        for (int ni = 0; ni < NI; ++ni) {
            int col = n0 + wn + ni * 16 + l16;
            float bv = bias ? bias[col] : 0.0f;
            #pragma unroll
            for (int r = 0; r < 4; ++r) {
                int row = m0 + wm + mi * 16 + quad * 4 + r;
                float x = acc[mi][ni][r] + bv;
                if (act) x = x / (1.0f + __expf(-x));
                size_t o = (size_t)row * N + col;
                if (Cf) Cf[o] = x;
                if (Cb) Cb[o] = f32_to_bf16(x);
            }
        }
    }
}

// ---------------------------------------------------------------------------
// Transpose + convert: src (R x C, row stride ld, fp32 or bf16) -> dst bf16
// (C x R, row stride ldd). grid (C/32, R/32), block (32, 8).
// ---------------------------------------------------------------------------
template<typename ST>
__global__ __launch_bounds__(256) void transpose_conv_kernel(
    const ST* __restrict__ src, int ld, short* __restrict__ dst, int ldd)
{
    __shared__ float tile[32][33];
    int r0 = blockIdx.y * 32, c0 = blockIdx.x * 32;
    int x = threadIdx.x, y = threadIdx.y;
    #pragma unroll
    for (int i = 0; i < 4; ++i) {
        ST v = src[(size_t)(r0 + y + i * 8) * ld + c0 + x];
        if (sizeof(ST) == 2) tile[y + i * 8][x] = bf16_to_f32((short)v);
        else                 tile[y + i * 8][x] = (float)v;
    }
    __syncthreads();
    #pragma unroll
    for (int i = 0; i < 4; ++i)
        dst[(size_t)(c0 + y + i * 8) * ldd + r0 + x] = f32_to_bf16(tile[x][y + i * 8]);
}

// fp32 -> bf16 elementwise (n multiple of 1024)
__global__ void conv_bf16_kernel(const float* __restrict__ src, short* __restrict__ dst)
{
    int i = blockIdx.x * blockDim.x + threadIdx.x;
    float4 v = ((const float4*)src)[i];
    short o[4] = {f32_to_bf16(v.x), f32_to_bf16(v.y), f32_to_bf16(v.z), f32_to_bf16(v.w)};
    *(uint2*)(dst + (size_t)i * 4) = *(const uint2*)o;
}

// ---------------------------------------------------------------------------
// Causal prefix EMA, windowed (beta^192 ~ 2e-9), ILP-batched loads (16 deep).
// grid (T/128, D/256), block 256.
// ---------------------------------------------------------------------------
__global__ __launch_bounds__(256) void ema_kernel(const float* __restrict__ hs,
                                                  float* __restrict__ l2)
{
    int d = blockIdx.y * 256 + threadIdx.x;
    int t0 = blockIdx.x * 128;
    int ts = t0 - 192; if (ts < 0) ts = 0;
    float m = 0.0f;
    for (int tb = ts; tb < t0; tb += 16) {
        float buf[16];
        #pragma unroll
        for (int j = 0; j < 16; ++j) buf[j] = hs[(size_t)(tb + j) * D_MODEL + d];
        #pragma unroll
        for (int j = 0; j < 16; ++j) m = 0.9f * m + 0.1f * buf[j];
    }
    for (int tb = t0; tb < t0 + 128; tb += 16) {
        float buf[16];
        #pragma unroll
        for (int j = 0; j < 16; ++j) buf[j] = hs[(size_t)(tb + j) * D_MODEL + d];
        #pragma unroll
        for (int j = 0; j < 16; ++j) { m = 0.9f * m + 0.1f * buf[j]; buf[j] = m; }
        #pragma unroll
        for (int j = 0; j < 16; ++j) l2[(size_t)(tb + j) * D_MODEL + d] = buf[j];
    }
}

// Router head on bf16 h: logits = h @ Wr2 + br2, 2-way softmax. 1 wave/row.
__global__ __launch_bounds__(64) void lam_kernel(
    const short* __restrict__ h, const float* __restrict__ Wr2,
    const float* __restrict__ br2, float* __restrict__ lam)
{
    int t = blockIdx.x;
    int lane = threadIdx.x;
    float z0 = 0.0f, z1 = 0.0f;
    for (int i = lane; i < 1024; i += 64) {
        float hv = bf16_to_f32(h[(size_t)t * 1024 + i]);
        z0 += hv * Wr2[i * 2 + 0];
        z1 += hv * Wr2[i * 2 + 1];
    }
    #pragma unroll
    for (int off = 1; off < 64; off <<= 1) {
        z0 += __shfl_xor(z0, off);
        z1 += __shfl_xor(z1, off);
    }
    if (lane == 0) {
        z0 += br2[0]; z1 += br2[1];
        float mx = fmaxf(z0, z1);
        float e0 = expf(z0 - mx), e1 = expf(z1 - mx);
        float inv = 1.0f / (e0 + e1);
        lam[t * 2 + 0] = e0 * inv;
        lam[t * 2 + 1] = e1 * inv;
    }
}

// fused = lam0*hs + lam1*l2 -> bf16
__global__ void fuse_kernel(const float* __restrict__ hs, const float* __restrict__ l2,
                            const float* __restrict__ lam, short* __restrict__ fused)
{
    int idx = blockIdx.x * blockDim.x + threadIdx.x;   // T*D/4
    int t = idx >> 9;
    float a0 = lam[t * 2 + 0], a1 = lam[t * 2 + 1];
    float4 a = ((const float4*)hs)[idx];
    float4 b = ((const float4*)l2)[idx];
    short o[4] = {f32_to_bf16(a0 * a.x + a1 * b.x), f32_to_bf16(a0 * a.y + a1 * b.y),
                  f32_to_bf16(a0 * a.z + a1 * b.z), f32_to_bf16(a0 * a.w + a1 * b.w)};
    *(uint2*)(fused + (size_t)idx * 4) = *(const uint2*)o;
}

// RoPE on q (bf16 T x 2048) -> (H, T, HD) bf16, paired halves per thread.
__global__ void rope_q_kernel(const short* __restrict__ q, short* __restrict__ qr)
{
    int idx = blockIdx.x * blockDim.x + threadIdx.x;   // T*NH*64
    int d = idx & 63;
    int h = (idx >> 6) & 15;
    int t = idx >> 10;
    float fr = (float)t * __expf(-(float)d * 0.14391156831212787f);
    float s, c;
    sincosf(fr, &s, &c);
    const short* src = q + (size_t)t * D_MODEL + h * HD;
    float x1 = bf16_to_f32(src[d]), x2 = bf16_to_f32(src[d + 64]);
    short* dst = qr + ((size_t)h * T_SEQ + t) * HD;
    dst[d]      = f32_to_bf16(x1 * c - x2 * s);
    dst[d + 64] = f32_to_bf16(x2 * c + x1 * s);
}

// RoPE on k-half of kv (bf16 T x 1024) -> (KVH, T, HD) bf16.
__global__ void rope_k_kernel(const short* __restrict__ kv, short* __restrict__ kr)
{
    int idx = blockIdx.x * blockDim.x + threadIdx.x;   // T*NKVH*64
    int d = idx & 63;
    int kh = (idx >> 6) & 3;
    int t = idx >> 8;
    float fr = (float)t * __expf(-(float)d * 0.14391156831212787f);
    float s, c;
    sincosf(fr, &s, &c);
    const short* src = kv + (size_t)t * 1024 + kh * HD;
    float x1 = bf16_to_f32(src[d]), x2 = bf16_to_f32(src[d + 64]);
    short* dst = kr + ((size_t)kh * T_SEQ + t) * HD;
    dst[d]      = f32_to_bf16(x1 * c - x2 * s);
    dst[d + 64] = f32_to_bf16(x2 * c + x1 * s);
}

// ---------------------------------------------------------------------------
// Causal flash attention. Block = (qt, h): 64 q rows, 4 waves x 16 rows.
// KV tile 64. K in (kvh, T, HD) bf16; V pre-transposed (kvh, HD, T) bf16.
// Out bf16 (T, H*HD).
// ---------------------------------------------------------------------------
__global__ __launch_bounds__(256) void attn_kernel(
    const short* __restrict__ Qr, const short* __restrict__ Kr,
    const short* __restrict__ Vt, short* __restrict__ Out)
{
    const int qt = blockIdx.x, h = blockIdx.y, kvh = h >> 2;
    const int tid = threadIdx.x, wave = tid >> 6, lane = tid & 63;
    const int l16 = lane & 15, quad = lane >> 4;

    __shared__ short Klds[64][136];   // [kv][hd], 272B rows (16B-mult, 2-way max)
    __shared__ short Vlds[128][72];   // [hd][kv], 144B rows
    __shared__ short Plds[4][16][72]; // per-wave P [qrow][kv]

    const int qbase = qt * 64 + wave * 16;
    bf16x8 qf[4];
    {
        const short* qrow = Qr + ((size_t)h * T_SEQ + qbase + l16) * HD;
        #pragma unroll
        for (int kc = 0; kc < 4; ++kc)
            qf[kc] = *(const bf16x8*)&qrow[kc * 32 + quad * 8];
    }

    f32x4 o[8] = {};
    float m_i[4], l_i[4];
    #pragma unroll
    for (int r = 0; r < 4; ++r) { m_i[r] = -1e30f; l_i[r] = 0.0f; }
    const float scale = 0.08838834764831845f;

    const short* kbase = Kr + (size_t)kvh * T_SEQ * HD;
    const short* vbase = Vt + (size_t)kvh * HD * T_SEQ;

    for (int kv0 = 0; kv0 < qt * 64 + 64; kv0 += 64) {
        // stage K 64x128 (contiguous 16KB in global) and V^T 128x64
        const short* ks = kbase + (size_t)kv0 * HD;
        #pragma unroll
        for (int p = 0; p < 4; ++p) {
            int li = p * 256 + tid;
            int row = li >> 4, off = (li & 15) * 8;
            *(uint4*)&Klds[row][off] = *(const uint4*)&ks[(size_t)row * HD + off];
        }
        #pragma unroll
        for (int p = 0; p < 4; ++p) {
            int li = p * 256 + tid;
            int row = li >> 3, off = (li & 7) * 8;
            *(uint4*)&Vlds[row][off] = *(const uint4*)&vbase[(size_t)row * T_SEQ + kv0 + off];
        }
        __syncthreads();

        // S = Q K^T  (4 kv subtiles of 16)
        f32x4 s[4] = {};
        #pragma unroll
        for (int ni = 0; ni < 4; ++ni)
            #pragma unroll
            for (int kc = 0; kc < 4; ++kc) {
                bf16x8 b = *(const bf16x8*)&Klds[ni * 16 + l16][kc * 32 + quad * 8];
                s[ni] = __builtin_amdgcn_mfma_f32_16x16x32_bf16(qf[kc], b, s[ni], 0, 0, 0);
            }

        float alpha[4];
        #pragma unroll
        for (int r = 0; r < 4; ++r) {
            int qg = qbase + quad * 4 + r;
            float sv[4];
            #pragma unroll
            for (int ni = 0; ni < 4; ++ni) {
                sv[ni] = s[ni][r] * scale;
                if (kv0 + ni * 16 + l16 > qg) sv[ni] = -1e30f;
            }
            float vm = fmaxf(fmaxf(sv[0], sv[1]), fmaxf(sv[2], sv[3]));
            #pragma unroll
            for (int off = 1; off < 16; off <<= 1) vm = fmaxf(vm, __shfl_xor(vm, off));
            float mn = fmaxf(m_i[r], vm);
            alpha[r] = __expf(m_i[r] - mn);
            float rs = 0.0f;
            #pragma unroll
            for (int ni = 0; ni < 4; ++ni) {
                float pv = __expf(sv[ni] - mn);
                rs += pv;
                Plds[wave][quad * 4 + r][ni * 16 + l16] = f32_to_bf16(pv);
            }
            #pragma unroll
            for (int off = 1; off < 16; off <<= 1) rs += __shfl_xor(rs, off);
            l_i[r] = alpha[r] * l_i[r] + rs;
            m_i[r] = mn;
        }
        asm volatile("s_waitcnt lgkmcnt(0)" ::: "memory");
        #pragma unroll
        for (int d8 = 0; d8 < 8; ++d8)
            #pragma unroll
            for (int r = 0; r < 4; ++r) o[d8][r] *= alpha[r];
        bf16x8 pa0 = *(const bf16x8*)&Plds[wave][l16][quad * 8];
        bf16x8 pa1 = *(const bf16x8*)&Plds[wave][l16][32 + quad * 8];
        #pragma unroll
        for (int d8 = 0; d8 < 8; ++d8) {
            bf16x8 b0 = *(const bf16x8*)&Vlds[d8 * 16 + l16][quad * 8];
            bf16x8 b1 = *(const bf16x8*)&Vlds[d8 * 16 + l16][32 + quad * 8];
            o[d8] = __builtin_amdgcn_mfma_f32_16x16x32_bf16(pa0, b0, o[d8], 0, 0, 0);
            o[d8] = __builtin_amdgcn_mfma_f32_16x16x32_bf16(pa1, b1, o[d8], 0, 0, 0);
        }
        __syncthreads();
    }

    #pragma unroll
    for (int d8 = 0; d8 < 8; ++d8)
        #pragma unroll
        for (int r = 0; r < 4; ++r) {
            int row = qbase + quad * 4 + r;
            Out[(size_t)row * D_MODEL + h * HD + d8 * 16 + l16] =
                f32_to_bf16(o[d8][r] / l_i[r]);
        }
}

// ---------------------------------------------------------------------------
extern "C" void kernel_launch(void* const* d_in, const int* in_sizes, int n_in,
                              void* d_out, int out_size, void* d_ws, size_t ws_size,
                              hipStream_t stream)
{
    const float* hs  = (const float*)d_in[0];
    const float* Wq  = (const float*)d_in[1];
    const float* Wk  = (const float*)d_in[2];
    const float* Wv  = (const float*)d_in[3];
    const float* Wo  = (const float*)d_in[4];
    const float* Wr1 = (const float*)d_in[5];
    const float* br1 = (const float*)d_in[6];
    const float* Wr2 = (const float*)d_in[7];
    const float* br2 = (const float*)d_in[8];
    float* out = (float*)d_out;

    char* w = (char*)d_ws;
    const size_t MB = 1u << 20;
    float* l2_f     = (float*)(w + 0 * MB);    // 16 MB
    short* hs_bf    = (short*)(w + 16 * MB);   // 8 MB (aliased as attn_bf later)
    short* Wq_t     = (short*)(w + 24 * MB);   // 8 MB
    short* Wkv_t    = (short*)(w + 32 * MB);   // 4 MB  [Wk^T | Wv^T]
    short* Wr1_t    = (short*)(w + 36 * MB);   // 4 MB
    short* Wo_t     = (short*)(w + 40 * MB);   // 8 MB
    short* q_bf     = (short*)(w + 48 * MB);   // 8 MB
    short* h_bf     = (short*)(w + 56 * MB);   // 4 MB
    short* fused_bf = (short*)(w + 60 * MB);   // 8 MB
    short* kv_bf    = (short*)(w + 68 * MB);   // 4 MB
    short* qr       = (short*)(w + 72 * MB);   // 8 MB (H,T,HD)
    short* kr       = (short*)(w + 80 * MB);   // 2 MB (KVH,T,HD)
    short* vr       = (short*)(w + 82 * MB);   // 2 MB (KVH,HD,T)
    float* lam_f    = (float*)(w + 84 * MB);   // 16 KB
    short* attn_bf  = hs_bf;                   // alias: hs_bf dead after q-gemm

    dim3 tb(32, 8);

    // weight transposes + input convert (independent)
    transpose_conv_kernel<float><<<dim3(64, 64), tb, 0, stream>>>(Wq, 2048, Wq_t, 2048);
    transpose_conv_kernel<float><<<dim3(16, 64), tb, 0, stream>>>(Wk, 512, Wkv_t, 2048);
    transpose_conv_kernel<float><<<dim3(16, 64), tb, 0, stream>>>(Wv, 512, Wkv_t + (size_t)512 * 2048, 2048);
    transpose_conv_kernel<float><<<dim3(32, 64), tb, 0, stream>>>(Wr1, 1024, Wr1_t, 2048);
    transpose_conv_kernel<float><<<dim3(64, 64), tb, 0, stream>>>(Wo, 2048, Wo_t, 2048);
    conv_bf16_kernel<<<(T_SEQ * D_MODEL / 4) / 256, 256, 0, stream>>>(hs, hs_bf);

    // l2 = causal EMA
    ema_kernel<<<dim3(T_SEQ / 128, D_MODEL / 256), 256, 0, stream>>>(hs, l2_f);

    // q = hs @ Wq  (bf16 out)
    gemm_bt_kernel<128><<<dim3(16, 16), 256, 0, stream>>>(
        hs_bf, Wq_t, nullptr, q_bf, 2048, 2048, 2048, nullptr, 0);

    // h = silu(q @ Wr1 + br1) (bf16 out)
    gemm_bt_kernel<64><<<dim3(8, 32), 256, 0, stream>>>(
        q_bf, Wr1_t, nullptr, h_bf, 2048, 1024, 2048, br1, 1);

    // lam = softmax(h @ Wr2 + br2)
    lam_kernel<<<T_SEQ, 64, 0, stream>>>(h_bf, Wr2, br2, lam_f);

    // fused = lam0*hs + lam1*l2 (bf16 out)
    fuse_kernel<<<(T_SEQ * D_MODEL / 4) / 256, 256, 0, stream>>>(hs, l2_f, lam_f, fused_bf);

    // [k|v] = fused @ [Wk|Wv] (bf16 out)
    gemm_bt_kernel<64><<<dim3(8, 32), 256, 0, stream>>>(
        fused_bf, Wkv_t, nullptr, kv_bf, 2048, 1024, 2048, nullptr, 0);

    // RoPE + head-major repack; V transposed to (KVH, HD, T)
    rope_q_kernel<<<(T_SEQ * NH * 64) / 256, 256, 0, stream>>>(q_bf, qr);
    rope_k_kernel<<<(T_SEQ * NKVH * 64) / 256, 256, 0, stream>>>(kv_bf, kr);
    transpose_conv_kernel<short><<<dim3(16, 64), tb, 0, stream>>>(kv_bf + 512, 1024, vr, 2048);

    // causal flash attention (bf16 out)
    attn_kernel<<<dim3(T_SEQ / 64, NH), 256, 0, stream>>>(qr, kr, vr, attn_bf);

    // out = attn @ Wo (fp32 out)
    gemm_bt_kernel<128><<<dim3(16, 16), 256, 0, stream>>>(
        attn_bf, Wo_t, out, nullptr, 2048, 2048, 2048, nullptr, 0);
}

// Round 3
// 380.438 us; speedup vs baseline: 2.8031x; 1.2406x over previous
//
#include <hip/hip_runtime.h>
#include <hip/hip_bf16.h>

#define T_SEQ 2048
#define D_MODEL 2048
#define NH 16
#define NKVH 4
#define HD 128

typedef __attribute__((ext_vector_type(8))) short bf16x8;
typedef __attribute__((ext_vector_type(4))) float f32x4;

static __device__ __forceinline__ short f32_to_bf16(float f) {
    unsigned u = __float_as_uint(f);
    u += 0x7fffu + ((u >> 16) & 1u);
    return (short)(u >> 16);
}
static __device__ __forceinline__ float bf16_to_f32(short s) {
    return __uint_as_float(((unsigned)(unsigned short)s) << 16);
}
static __device__ __forceinline__ void gl_to_lds16(const void* g, void* l) {
    __builtin_amdgcn_global_load_lds(
        (const __attribute__((address_space(1))) unsigned int*)g,
        (__attribute__((address_space(3))) unsigned int*)l, 16, 0, 0);
}

// ---------------------------------------------------------------------------
// m97-style GEMM: A bf16 (M x K), Bt bf16 (N x K), BK=32, BN=128.
// ---------------------------------------------------------------------------
template<int BM>
__global__ __launch_bounds__(256) void gemm_bt_kernel(
    const short* __restrict__ A, const short* __restrict__ Bt,
    float* __restrict__ Cf, short* __restrict__ Cb,
    int M, int N, int K, const float* __restrict__ bias, int act)
{
    constexpr int NI = (BM == 128) ? 4 : 2;
    __shared__ short Alds[BM * 32];
    __shared__ short Blds[128 * 32];

    const int tid = threadIdx.x;
    const int wave = tid >> 6, lane = tid & 63;
    const int l16 = lane & 15, quad = lane >> 4;
    const int wm = (BM == 128) ? (wave >> 1) * 64 : 0;
    const int wn = (BM == 128) ? (wave & 1) * 64 : wave * 32;
    const int m0 = blockIdx.y * BM, n0 = blockIdx.x * 128;

    f32x4 acc[4][NI] = {};

    for (int k0 = 0; k0 < K; k0 += 32) {
        if (BM == 128) {
            #pragma unroll
            for (int p = 0; p < 2; ++p) {
                int li = p * 256 + tid;
                gl_to_lds16(A + (size_t)(m0 + (li >> 2)) * K + k0 + (li & 3) * 8,
                            Alds + (size_t)(p * 256 + wave * 64) * 8);
            }
        } else {
            gl_to_lds16(A + (size_t)(m0 + (tid >> 2)) * K + k0 + (tid & 3) * 8,
                        Alds + (size_t)(wave * 64) * 8);
        }
        #pragma unroll
        for (int p = 0; p < 2; ++p) {
            int li = p * 256 + tid;
            gl_to_lds16(Bt + (size_t)(n0 + (li >> 2)) * K + k0 + (li & 3) * 8,
                        Blds + (size_t)(p * 256 + wave * 64) * 8);
        }
        __syncthreads();

        bf16x8 a[4], b[NI];
        #pragma unroll
        for (int i = 0; i < 4; ++i)
            a[i] = *(const bf16x8*)&Alds[(wm + i * 16 + l16) * 32 + quad * 8];
        #pragma unroll
        for (int i = 0; i < NI; ++i)
            b[i] = *(const bf16x8*)&Blds[(wn + i * 16 + l16) * 32 + quad * 8];
        #pragma unroll
        for (int mi = 0; mi < 4; ++mi)
            #pragma unroll
            for (int ni = 0; ni < NI; ++ni)
                acc[mi][ni] = __builtin_amdgcn_mfma_f32_16x16x32_bf16(
                    a[mi], b[ni], acc[mi][ni], 0, 0, 0);
        __syncthreads();
    }

    #pragma unroll
    for (int mi = 0; mi < 4; ++mi) {
        #pragma unroll
        for (int ni = 0; ni < NI; ++ni) {
            int col = n0 + wn + ni * 16 + l16;
            float bv = bias ? bias[col] : 0.0f;
            #pragma unroll
            for (int r = 0; r < 4; ++r) {
                int row = m0 + wm + mi * 16 + quad * 4 + r;
                float x = acc[mi][ni][r] + bv;
                if (act) x = x / (1.0f + __expf(-x));
                size_t o = (size_t)row * N + col;
                if (Cf) Cf[o] = x;
                if (Cb) Cb[o] = f32_to_bf16(x);
            }
        }
    }
}

// ---------------------------------------------------------------------------
// Transpose + convert: src (R x C, row stride ld) -> dst bf16 (C x R, ldd).
// grid (C/32, R/32), block (32, 8).
// ---------------------------------------------------------------------------
template<typename ST>
__global__ __launch_bounds__(256) void transpose_conv_kernel(
    const ST* __restrict__ src, int ld, short* __restrict__ dst, int ldd)
{
    __shared__ float tile[32][33];
    int r0 = blockIdx.y * 32, c0 = blockIdx.x * 32;
    int x = threadIdx.x, y = threadIdx.y;
    #pragma unroll
    for (int i = 0; i < 4; ++i) {
        ST v = src[(size_t)(r0 + y + i * 8) * ld + c0 + x];
        if (sizeof(ST) == 2) tile[y + i * 8][x] = bf16_to_f32((short)v);
        else                 tile[y + i * 8][x] = (float)v;
    }
    __syncthreads();
    #pragma unroll
    for (int i = 0; i < 4; ++i)
        dst[(size_t)(c0 + y + i * 8) * ldd + r0 + x] = f32_to_bf16(tile[x][y + i * 8]);
}

// fp32 -> bf16 elementwise
__global__ void conv_bf16_kernel(const float* __restrict__ src, short* __restrict__ dst)
{
    int i = blockIdx.x * blockDim.x + threadIdx.x;
    float4 v = ((const float4*)src)[i];
    short o[4] = {f32_to_bf16(v.x), f32_to_bf16(v.y), f32_to_bf16(v.z), f32_to_bf16(v.w)};
    *(uint2*)(dst + (size_t)i * 4) = *(const uint2*)o;
}

// ---------------------------------------------------------------------------
// Causal prefix EMA, windowed (beta^192 ~ 2e-9), ILP-batched loads (16 deep).
// ---------------------------------------------------------------------------
__global__ __launch_bounds__(256) void ema_kernel(const float* __restrict__ hs,
                                                  float* __restrict__ l2)
{
    int d = blockIdx.y * 256 + threadIdx.x;
    int t0 = blockIdx.x * 128;
    int ts = t0 - 192; if (ts < 0) ts = 0;
    float m = 0.0f;
    for (int tb = ts; tb < t0; tb += 16) {
        float buf[16];
        #pragma unroll
        for (int j = 0; j < 16; ++j) buf[j] = hs[(size_t)(tb + j) * D_MODEL + d];
        #pragma unroll
        for (int j = 0; j < 16; ++j) m = 0.9f * m + 0.1f * buf[j];
    }
    for (int tb = t0; tb < t0 + 128; tb += 16) {
        float buf[16];
        #pragma unroll
        for (int j = 0; j < 16; ++j) buf[j] = hs[(size_t)(tb + j) * D_MODEL + d];
        #pragma unroll
        for (int j = 0; j < 16; ++j) { m = 0.9f * m + 0.1f * buf[j]; buf[j] = m; }
        #pragma unroll
        for (int j = 0; j < 16; ++j) l2[(size_t)(tb + j) * D_MODEL + d] = buf[j];
    }
}

// Router head: logits = h @ Wr2 + br2, 2-way softmax. 1 wave/row.
__global__ __launch_bounds__(64) void lam_kernel(
    const short* __restrict__ h, const float* __restrict__ Wr2,
    const float* __restrict__ br2, float* __restrict__ lam)
{
    int t = blockIdx.x;
    int lane = threadIdx.x;
    float z0 = 0.0f, z1 = 0.0f;
    for (int i = lane; i < 1024; i += 64) {
        float hv = bf16_to_f32(h[(size_t)t * 1024 + i]);
        z0 += hv * Wr2[i * 2 + 0];
        z1 += hv * Wr2[i * 2 + 1];
    }
    #pragma unroll
    for (int off = 1; off < 64; off <<= 1) {
        z0 += __shfl_xor(z0, off);
        z1 += __shfl_xor(z1, off);
    }
    if (lane == 0) {
        z0 += br2[0]; z1 += br2[1];
        float mx = fmaxf(z0, z1);
        float e0 = expf(z0 - mx), e1 = expf(z1 - mx);
        float inv = 1.0f / (e0 + e1);
        lam[t * 2 + 0] = e0 * inv;
        lam[t * 2 + 1] = e1 * inv;
    }
}

// fused = lam0*hs + lam1*l2 -> bf16
__global__ void fuse_kernel(const float* __restrict__ hs, const float* __restrict__ l2,
                            const float* __restrict__ lam, short* __restrict__ fused)
{
    int idx = blockIdx.x * blockDim.x + threadIdx.x;
    int t = idx >> 9;
    float a0 = lam[t * 2 + 0], a1 = lam[t * 2 + 1];
    float4 a = ((const float4*)hs)[idx];
    float4 b = ((const float4*)l2)[idx];
    short o[4] = {f32_to_bf16(a0 * a.x + a1 * b.x), f32_to_bf16(a0 * a.y + a1 * b.y),
                  f32_to_bf16(a0 * a.z + a1 * b.z), f32_to_bf16(a0 * a.w + a1 * b.w)};
    *(uint2*)(fused + (size_t)idx * 4) = *(const uint2*)o;
}

// RoPE on q -> (H, T, HD) bf16, with 1/sqrt(HD) folded in.
__global__ void rope_q_kernel(const short* __restrict__ q, short* __restrict__ qr)
{
    int idx = blockIdx.x * blockDim.x + threadIdx.x;   // T*NH*64
    int d = idx & 63;
    int h = (idx >> 6) & 15;
    int t = idx >> 10;
    float fr = (float)t * __expf(-(float)d * 0.14391156831212787f);
    float s, c;
    sincosf(fr, &s, &c);
    const float sc = 0.08838834764831845f;  // 1/sqrt(128)
    const short* src = q + (size_t)t * D_MODEL + h * HD;
    float x1 = bf16_to_f32(src[d]) * sc, x2 = bf16_to_f32(src[d + 64]) * sc;
    short* dst = qr + ((size_t)h * T_SEQ + t) * HD;
    dst[d]      = f32_to_bf16(x1 * c - x2 * s);
    dst[d + 64] = f32_to_bf16(x2 * c + x1 * s);
}

// RoPE on k-half of kv (bf16 T x 1024) -> (KVH, T, HD) bf16.
__global__ void rope_k_kernel(const short* __restrict__ kv, short* __restrict__ kr)
{
    int idx = blockIdx.x * blockDim.x + threadIdx.x;   // T*NKVH*64
    int d = idx & 63;
    int kh = (idx >> 6) & 3;
    int t = idx >> 8;
    float fr = (float)t * __expf(-(float)d * 0.14391156831212787f);
    float s, c;
    sincosf(fr, &s, &c);
    const short* src = kv + (size_t)t * 1024 + kh * HD;
    float x1 = bf16_to_f32(src[d]), x2 = bf16_to_f32(src[d + 64]);
    short* dst = kr + ((size_t)kh * T_SEQ + t) * HD;
    dst[d]      = f32_to_bf16(x1 * c - x2 * s);
    dst[d + 64] = f32_to_bf16(x2 * c + x1 * s);
}

// ---------------------------------------------------------------------------
// Causal flash attention, max-free softmax, paired q-tiles for load balance.
// Block (pi, h): phase 0 -> q-tile pi, phase 1 -> q-tile 31-pi; every block
// does exactly 17 KV-128 iterations. 4 waves x 16 q-rows. Double-buffered
// global_load_lds staging with xor-swizzled 16B chunks (conflict-free b128).
// Q pre-scaled by 1/sqrt(HD). K (kvh,T,HD); V^T (kvh,HD,T). Out bf16.
// ---------------------------------------------------------------------------
__global__ __launch_bounds__(256, 1) void attn_kernel(
    const short* __restrict__ Qr, const short* __restrict__ Kr,
    const short* __restrict__ Vt, short* __restrict__ Out)
{
    const int pi = blockIdx.x;          // 0..15
    const int h = blockIdx.y;
    const int kvh = h >> 2;
    const int tid = threadIdx.x;
    const int wave = tid >> 6, lane = tid & 63;
    const int l16 = lane & 15, quad = lane >> 4;

    __shared__ short Klds[2][128 * 128];   // 64 KB, swizzled chunks
    __shared__ short Vlds[2][128 * 128];   // 64 KB, [hd][kv] swizzled
    __shared__ short Plds[4][16][136];     // 17 KB, padded (+8)

    const short* kbase = Kr + (size_t)kvh * T_SEQ * HD;
    const short* vbase = Vt + (size_t)kvh * HD * T_SEQ;

    for (int ph = 0; ph < 2; ++ph) {
        const int qt = ph ? (31 - pi) : pi;
        const int qbase = qt * 64 + wave * 16;
        const int n = (qt * 64 + 191) >> 7;     // ceil((qt+1)*64 / 128)

        bf16x8 qf[4];
        {
            const short* qrow = Qr + ((size_t)h * T_SEQ + qbase + l16) * HD;
            #pragma unroll
            for (int kc = 0; kc < 4; ++kc)
                qf[kc] = *(const bf16x8*)&qrow[kc * 32 + quad * 8];
        }
        f32x4 o[8] = {};
        float lsum[4] = {0.0f, 0.0f, 0.0f, 0.0f};

        __syncthreads();   // previous phase fully done with LDS

        // stage tile 0 into buf 0 (16B chunks, chunk c of row r at slot c^(r&15))
        {
            const short* ks = kbase;
            #pragma unroll
            for (int p = 0; p < 8; ++p) {
                int li = p * 256 + tid;
                int row = li >> 4, gs = (li & 15) ^ (row & 15);
                gl_to_lds16(ks + (size_t)row * HD + gs * 8,
                            &Klds[0][(size_t)(p * 256 + wave * 64) * 8]);
            }
            #pragma unroll
            for (int p = 0; p < 8; ++p) {
                int li = p * 256 + tid;
                int row = li >> 4, gs = (li & 15) ^ (row & 15);
                gl_to_lds16(vbase + (size_t)row * T_SEQ + gs * 8,
                            &Vlds[0][(size_t)(p * 256 + wave * 64) * 8]);
            }
        }

        for (int t = 0; t < n; ++t) {
            // tile t staged (vmcnt) + all waves done reading buf !(t&1)
            asm volatile("s_waitcnt vmcnt(0)\n\ts_barrier" ::: "memory");

            if (t + 1 < n) {   // prefetch next tile; overlaps compute below
                int kv1 = (t + 1) << 7;
                int nb = (t + 1) & 1;
                const short* ks = kbase + (size_t)kv1 * HD;
                #pragma unroll
                for (int p = 0; p < 8; ++p) {
                    int li = p * 256 + tid;
                    int row = li >> 4, gs = (li & 15) ^ (row & 15);
                    gl_to_lds16(ks + (size_t)row * HD + gs * 8,
                                &Klds[nb][(size_t)(p * 256 + wave * 64) * 8]);
                }
                #pragma unroll
                for (int p = 0; p < 8; ++p) {
                    int li = p * 256 + tid;
                    int row = li >> 4, gs = (li & 15) ^ (row & 15);
                    gl_to_lds16(vbase + (size_t)row * T_SEQ + kv1 + gs * 8,
                                &Vlds[nb][(size_t)(p * 256 + wave * 64) * 8]);
                }
            }

            const short* Kb = Klds[t & 1];
            const short* Vb = Vlds[t & 1];

            // S = Q K^T : 8 kv-subtiles x 4 k-chunks
            f32x4 s[8];
            #pragma unroll
            for (int ni = 0; ni < 8; ++ni) s[ni] = (f32x4){0, 0, 0, 0};
            #pragma unroll
            for (int ni = 0; ni < 8; ++ni)
                #pragma unroll
                for (int kc = 0; kc < 4; ++kc) {
                    bf16x8 b = *(const bf16x8*)
                        &Kb[(size_t)(ni * 16 + l16) * 128 + (((kc * 4 + quad) ^ l16) * 8)];
                    s[ni] = __builtin_amdgcn_mfma_f32_16x16x32_bf16(qf[kc], b, s[ni], 0, 0, 0);
                }

            // max-free softmax: p = exp(s) (Q pre-scaled); per-lane l partials
            if (t == n - 1) {
                int kvg0 = t << 7;
                #pragma unroll
                for (int ni = 0; ni < 8; ++ni) {
                    int kvg = kvg0 + ni * 16 + l16;
                    #pragma unroll
                    for (int r = 0; r < 4; ++r) {
                        int qg = qbase + quad * 4 + r;
                        float p = (kvg <= qg) ? __expf(s[ni][r]) : 0.0f;
                        lsum[r] += p;
                        Plds[wave][quad * 4 + r][ni * 16 + l16] = f32_to_bf16(p);
                    }
                }
            } else {
                #pragma unroll
                for (int ni = 0; ni < 8; ++ni)
                    #pragma unroll
                    for (int r = 0; r < 4; ++r) {
                        float p = __expf(s[ni][r]);
                        lsum[r] += p;
                        Plds[wave][quad * 4 + r][ni * 16 + l16] = f32_to_bf16(p);
                    }
            }
            asm volatile("s_waitcnt lgkmcnt(0)" ::: "memory");

            // O += P V : 4 k-chunks x 8 d-subtiles
            #pragma unroll
            for (int kc = 0; kc < 4; ++kc) {
                bf16x8 pa = *(const bf16x8*)&Plds[wave][l16][kc * 32 + quad * 8];
                #pragma unroll
                for (int d8 = 0; d8 < 8; ++d8) {
                    bf16x8 b = *(const bf16x8*)
                        &Vb[(size_t)(d8 * 16 + l16) * 128 + (((kc * 4 + quad) ^ l16) * 8)];
                    o[d8] = __builtin_amdgcn_mfma_f32_16x16x32_bf16(pa, b, o[d8], 0, 0, 0);
                }
            }
        }

        // epilogue: one 16-lane l reduction, then normalize + store
        #pragma unroll
        for (int r = 0; r < 4; ++r) {
            #pragma unroll
            for (int off = 1; off < 16; off <<= 1)
                lsum[r] += __shfl_xor(lsum[r], off);
            lsum[r] = 1.0f / lsum[r];
        }
        #pragma unroll
        for (int d8 = 0; d8 < 8; ++d8)
            #pragma unroll
            for (int r = 0; r < 4; ++r) {
                int row = qbase + quad * 4 + r;
                Out[(size_t)row * D_MODEL + h * HD + d8 * 16 + l16] =
                    f32_to_bf16(o[d8][r] * lsum[r]);
            }
    }
}

// ---------------------------------------------------------------------------
extern "C" void kernel_launch(void* const* d_in, const int* in_sizes, int n_in,
                              void* d_out, int out_size, void* d_ws, size_t ws_size,
                              hipStream_t stream)
{
    const float* hs  = (const float*)d_in[0];
    const float* Wq  = (const float*)d_in[1];
    const float* Wk  = (const float*)d_in[2];
    const float* Wv  = (const float*)d_in[3];
    const float* Wo  = (const float*)d_in[4];
    const float* Wr1 = (const float*)d_in[5];
    const float* br1 = (const float*)d_in[6];
    const float* Wr2 = (const float*)d_in[7];
    const float* br2 = (const float*)d_in[8];
    float* out = (float*)d_out;

    char* w = (char*)d_ws;
    const size_t MB = 1u << 20;
    float* l2_f     = (float*)(w + 0 * MB);    // 16 MB
    short* hs_bf    = (short*)(w + 16 * MB);   // 8 MB (aliased as attn_bf later)
    short* Wq_t     = (short*)(w + 24 * MB);   // 8 MB
    short* Wkv_t    = (short*)(w + 32 * MB);   // 4 MB  [Wk^T | Wv^T]
    short* Wr1_t    = (short*)(w + 36 * MB);   // 4 MB
    short* Wo_t     = (short*)(w + 40 * MB);   // 8 MB
    short* q_bf     = (short*)(w + 48 * MB);   // 8 MB
    short* h_bf     = (short*)(w + 56 * MB);   // 4 MB
    short* fused_bf = (short*)(w + 60 * MB);   // 8 MB
    short* kv_bf    = (short*)(w + 68 * MB);   // 4 MB
    short* qr       = (short*)(w + 72 * MB);   // 8 MB (H,T,HD), pre-scaled
    short* kr       = (short*)(w + 80 * MB);   // 2 MB (KVH,T,HD)
    short* vr       = (short*)(w + 82 * MB);   // 2 MB (KVH,HD,T)
    float* lam_f    = (float*)(w + 84 * MB);   // 16 KB
    short* attn_bf  = hs_bf;                   // alias: hs_bf dead after q-gemm

    dim3 tb(32, 8);

    transpose_conv_kernel<float><<<dim3(64, 64), tb, 0, stream>>>(Wq, 2048, Wq_t, 2048);
    transpose_conv_kernel<float><<<dim3(16, 64), tb, 0, stream>>>(Wk, 512, Wkv_t, 2048);
    transpose_conv_kernel<float><<<dim3(16, 64), tb, 0, stream>>>(Wv, 512, Wkv_t + (size_t)512 * 2048, 2048);
    transpose_conv_kernel<float><<<dim3(32, 64), tb, 0, stream>>>(Wr1, 1024, Wr1_t, 2048);
    transpose_conv_kernel<float><<<dim3(64, 64), tb, 0, stream>>>(Wo, 2048, Wo_t, 2048);
    conv_bf16_kernel<<<(T_SEQ * D_MODEL / 4) / 256, 256, 0, stream>>>(hs, hs_bf);

    ema_kernel<<<dim3(T_SEQ / 128, D_MODEL / 256), 256, 0, stream>>>(hs, l2_f);

    gemm_bt_kernel<128><<<dim3(16, 16), 256, 0, stream>>>(
        hs_bf, Wq_t, nullptr, q_bf, 2048, 2048, 2048, nullptr, 0);

    gemm_bt_kernel<64><<<dim3(8, 32), 256, 0, stream>>>(
        q_bf, Wr1_t, nullptr, h_bf, 2048, 1024, 2048, br1, 1);

    lam_kernel<<<T_SEQ, 64, 0, stream>>>(h_bf, Wr2, br2, lam_f);

    fuse_kernel<<<(T_SEQ * D_MODEL / 4) / 256, 256, 0, stream>>>(hs, l2_f, lam_f, fused_bf);

    gemm_bt_kernel<64><<<dim3(8, 32), 256, 0, stream>>>(
        fused_bf, Wkv_t, nullptr, kv_bf, 2048, 1024, 2048, nullptr, 0);

    rope_q_kernel<<<(T_SEQ * NH * 64) / 256, 256, 0, stream>>>(q_bf, qr);
    rope_k_kernel<<<(T_SEQ * NKVH * 64) / 256, 256, 0, stream>>>(kv_bf, kr);
    transpose_conv_kernel<short><<<dim3(16, 64), tb, 0, stream>>>(kv_bf + 512, 1024, vr, 2048);

    attn_kernel<<<dim3(16, NH), 256, 0, stream>>>(qr, kr, vr, attn_bf);

    gemm_bt_kernel<128><<<dim3(16, 16), 256, 0, stream>>>(
        attn_bf, Wo_t, out, nullptr, 2048, 2048, 2048, nullptr, 0);
}

// Round 4
// 349.453 us; speedup vs baseline: 3.0516x; 1.0887x over previous
//
#include <hip/hip_runtime.h>
#include <hip/hip_bf16.h>

#define T_SEQ 2048
#define D_MODEL 2048
#define NH 16
#define NKVH 4
#define HD 128

typedef __attribute__((ext_vector_type(8))) short bf16x8;
typedef __attribute__((ext_vector_type(4))) float f32x4;

static __device__ __forceinline__ short f32_to_bf16(float f) {
    unsigned u = __float_as_uint(f);
    u += 0x7fffu + ((u >> 16) & 1u);
    return (short)(u >> 16);
}
static __device__ __forceinline__ float bf16_to_f32(short s) {
    return __uint_as_float(((unsigned)(unsigned short)s) << 16);
}
static __device__ __forceinline__ void gl_to_lds16(const void* g, void* l) {
    __builtin_amdgcn_global_load_lds(
        (const __attribute__((address_space(1))) unsigned int*)g,
        (__attribute__((address_space(3))) unsigned int*)l, 16, 0, 0);
}

// ---------------------------------------------------------------------------
// Pipelined GEMM: A bf16 (M x K), Bt bf16 (N x K), BK=64, BN=128, double-
// buffered LDS, raw vmcnt(0)+s_barrier, prefetch-after-barrier (attn pattern).
// LDS chunks xor-swizzled: chunk c of row r lives at slot c^(r&7) ->
// conflict-free ds_read_b128 fragments. BM=128: 4 waves 2x2 of 64x64.
// BM=64: 4 waves 64x32.
// ---------------------------------------------------------------------------
template<int BM>
__global__ __launch_bounds__(256) void gemm_bt_kernel(
    const short* __restrict__ A, const short* __restrict__ Bt,
    float* __restrict__ Cf, short* __restrict__ Cb,
    int M, int N, int K, const float* __restrict__ bias, int act)
{
    constexpr int NI = (BM == 128) ? 4 : 2;
    constexpr int ACH = BM / 32;               // A chunks per thread (4 or 2)
    __shared__ short Alds[2][BM * 64];
    __shared__ short Blds[2][128 * 64];

    const int tid = threadIdx.x;
    const int wave = tid >> 6, lane = tid & 63;
    const int l16 = lane & 15, quad = lane >> 4;
    const int wm = (BM == 128) ? (wave >> 1) * 64 : 0;
    const int wn = (BM == 128) ? (wave & 1) * 64 : wave * 32;
    const int m0 = blockIdx.y * BM, n0 = blockIdx.x * 128;
    const int niter = K >> 6;

    f32x4 acc[4][NI] = {};

    // stage k-tile 0 into buf 0
    #pragma unroll
    for (int p = 0; p < ACH; ++p) {
        int li = p * 256 + tid;
        int row = li >> 3, sc = li & 7;
        gl_to_lds16(A + (size_t)(m0 + row) * K + ((sc ^ (row & 7)) * 8),
                    &Alds[0][(size_t)(p * 256 + wave * 64) * 8]);
    }
    #pragma unroll
    for (int p = 0; p < 4; ++p) {
        int li = p * 256 + tid;
        int row = li >> 3, sc = li & 7;
        gl_to_lds16(Bt + (size_t)(n0 + row) * K + ((sc ^ (row & 7)) * 8),
                    &Blds[0][(size_t)(p * 256 + wave * 64) * 8]);
    }

    for (int t = 0; t < niter; ++t) {
        // tile t staged (vmcnt) + all waves done reading the other buffer
        asm volatile("s_waitcnt vmcnt(0)\n\ts_barrier" ::: "memory");

        if (t + 1 < niter) {               // prefetch overlaps compute below
            int k1 = (t + 1) << 6;
            int nb = (t + 1) & 1;
            #pragma unroll
            for (int p = 0; p < ACH; ++p) {
                int li = p * 256 + tid;
                int row = li >> 3, sc = li & 7;
                gl_to_lds16(A + (size_t)(m0 + row) * K + k1 + ((sc ^ (row & 7)) * 8),
                            &Alds[nb][(size_t)(p * 256 + wave * 64) * 8]);
            }
            #pragma unroll
            for (int p = 0; p < 4; ++p) {
                int li = p * 256 + tid;
                int row = li >> 3, sc = li & 7;
                gl_to_lds16(Bt + (size_t)(n0 + row) * K + k1 + ((sc ^ (row & 7)) * 8),
                            &Blds[nb][(size_t)(p * 256 + wave * 64) * 8]);
            }
        }

        const short* Ab = Alds[t & 1];
        const short* Bb = Blds[t & 1];
        #pragma unroll
        for (int kk = 0; kk < 2; ++kk) {
            bf16x8 a[4], b[NI];
            #pragma unroll
            for (int i = 0; i < 4; ++i)
                a[i] = *(const bf16x8*)
                    &Ab[(size_t)(wm + i * 16 + l16) * 64 + (((kk * 4 + quad) ^ (l16 & 7)) * 8)];
            #pragma unroll
            for (int i = 0; i < NI; ++i)
                b[i] = *(const bf16x8*)
                    &Bb[(size_t)(wn + i * 16 + l16) * 64 + (((kk * 4 + quad) ^ (l16 & 7)) * 8)];
            #pragma unroll
            for (int mi = 0; mi < 4; ++mi)
                #pragma unroll
                for (int ni = 0; ni < NI; ++ni)
                    acc[mi][ni] = __builtin_amdgcn_mfma_f32_16x16x32_bf16(
                        a[mi], b[ni], acc[mi][ni], 0, 0, 0);
        }
    }

    #pragma unroll
    for (int mi = 0; mi < 4; ++mi) {
        #pragma unroll
        for (int ni = 0; ni < NI; ++ni) {
            int col = n0 + wn + ni * 16 + l16;
            float bv = bias ? bias[col] : 0.0f;
            #pragma unroll
            for (int r = 0; r < 4; ++r) {
                int row = m0 + wm + mi * 16 + quad * 4 + r;
                float x = acc[mi][ni][r] + bv;
                if (act) x = x / (1.0f + __expf(-x));
                size_t o = (size_t)row * N + col;
                if (Cf) Cf[o] = x;
                if (Cb) Cb[o] = f32_to_bf16(x);
            }
        }
    }
}

// ---------------------------------------------------------------------------
// All 5 weight transposes in one launch. src fp32 (2048 x C) -> dst bf16
// (C x 2048). grid (192, 64), block 256; x-ranges select the weight.
// ---------------------------------------------------------------------------
__global__ __launch_bounds__(256) void transpose_all_kernel(
    const float* __restrict__ Wq, const float* __restrict__ Wk,
    const float* __restrict__ Wv, const float* __restrict__ Wr1,
    const float* __restrict__ Wo, short* __restrict__ Wq_t,
    short* __restrict__ Wkv_t, short* __restrict__ Wr1_t,
    short* __restrict__ Wo_t)
{
    __shared__ float tile[32][33];
    int bx = blockIdx.x;
    const float* src; short* dst; int ld, cb;
    if (bx < 64)       { src = Wq;  dst = Wq_t;  ld = 2048; cb = bx; }
    else if (bx < 80)  { src = Wk;  dst = Wkv_t; ld = 512;  cb = bx - 64; }
    else if (bx < 96)  { src = Wv;  dst = Wkv_t + (size_t)512 * 2048; ld = 512; cb = bx - 80; }
    else if (bx < 128) { src = Wr1; dst = Wr1_t; ld = 1024; cb = bx - 96; }
    else               { src = Wo;  dst = Wo_t;  ld = 2048; cb = bx - 128; }
    int c0 = cb * 32, r0 = blockIdx.y * 32;
    int t = threadIdx.x;
    int r = t >> 3, c4 = (t & 7) * 4;
    float4 v = *(const float4*)&src[(size_t)(r0 + r) * ld + c0 + c4];
    tile[r][c4 + 0] = v.x; tile[r][c4 + 1] = v.y;
    tile[r][c4 + 2] = v.z; tile[r][c4 + 3] = v.w;
    __syncthreads();
    short o[4];
    #pragma unroll
    for (int j = 0; j < 4; ++j) o[j] = f32_to_bf16(tile[c4 + j][r]);
    *(uint2*)&dst[(size_t)(c0 + r) * 2048 + r0 + c4] = *(const uint2*)o;
}

// bf16 transpose: src (R x C, ld) -> dst (C x R, ldd). grid (C/32, R/32).
__global__ __launch_bounds__(256) void transpose_bf_kernel(
    const short* __restrict__ src, int ld, short* __restrict__ dst, int ldd)
{
    __shared__ float tile[32][33];
    int r0 = blockIdx.y * 32, c0 = blockIdx.x * 32;
    int x = threadIdx.x & 31, y = threadIdx.x >> 5;
    #pragma unroll
    for (int i = 0; i < 4; ++i)
        tile[y + i * 8][x] = bf16_to_f32(src[(size_t)(r0 + y + i * 8) * ld + c0 + x]);
    __syncthreads();
    #pragma unroll
    for (int i = 0; i < 4; ++i)
        dst[(size_t)(c0 + y + i * 8) * ldd + r0 + x] = f32_to_bf16(tile[x][y + i * 8]);
}

// fp32 -> bf16 elementwise
__global__ void conv_bf16_kernel(const float* __restrict__ src, short* __restrict__ dst)
{
    int i = blockIdx.x * blockDim.x + threadIdx.x;
    float4 v = ((const float4*)src)[i];
    short o[4] = {f32_to_bf16(v.x), f32_to_bf16(v.y), f32_to_bf16(v.z), f32_to_bf16(v.w)};
    *(uint2*)(dst + (size_t)i * 4) = *(const uint2*)o;
}

// ---------------------------------------------------------------------------
// Causal prefix EMA, windowed (beta^192 ~ 2e-9), ILP-batched loads (16 deep).
// ---------------------------------------------------------------------------
__global__ __launch_bounds__(256) void ema_kernel(const float* __restrict__ hs,
                                                  float* __restrict__ l2)
{
    int d = blockIdx.y * 256 + threadIdx.x;
    int t0 = blockIdx.x * 128;
    int ts = t0 - 192; if (ts < 0) ts = 0;
    float m = 0.0f;
    for (int tb = ts; tb < t0; tb += 16) {
        float buf[16];
        #pragma unroll
        for (int j = 0; j < 16; ++j) buf[j] = hs[(size_t)(tb + j) * D_MODEL + d];
        #pragma unroll
        for (int j = 0; j < 16; ++j) m = 0.9f * m + 0.1f * buf[j];
    }
    for (int tb = t0; tb < t0 + 128; tb += 16) {
        float buf[16];
        #pragma unroll
        for (int j = 0; j < 16; ++j) buf[j] = hs[(size_t)(tb + j) * D_MODEL + d];
        #pragma unroll
        for (int j = 0; j < 16; ++j) { m = 0.9f * m + 0.1f * buf[j]; buf[j] = m; }
        #pragma unroll
        for (int j = 0; j < 16; ++j) l2[(size_t)(tb + j) * D_MODEL + d] = buf[j];
    }
}

// Router head: logits = h @ Wr2 + br2, 2-way softmax. 1 wave/row.
__global__ __launch_bounds__(64) void lam_kernel(
    const short* __restrict__ h, const float* __restrict__ Wr2,
    const float* __restrict__ br2, float* __restrict__ lam)
{
    int t = blockIdx.x;
    int lane = threadIdx.x;
    float z0 = 0.0f, z1 = 0.0f;
    for (int i = lane; i < 1024; i += 64) {
        float hv = bf16_to_f32(h[(size_t)t * 1024 + i]);
        z0 += hv * Wr2[i * 2 + 0];
        z1 += hv * Wr2[i * 2 + 1];
    }
    #pragma unroll
    for (int off = 1; off < 64; off <<= 1) {
        z0 += __shfl_xor(z0, off);
        z1 += __shfl_xor(z1, off);
    }
    if (lane == 0) {
        z0 += br2[0]; z1 += br2[1];
        float mx = fmaxf(z0, z1);
        float e0 = expf(z0 - mx), e1 = expf(z1 - mx);
        float inv = 1.0f / (e0 + e1);
        lam[t * 2 + 0] = e0 * inv;
        lam[t * 2 + 1] = e1 * inv;
    }
}

// fused = lam0*hs + lam1*l2 -> bf16
__global__ void fuse_kernel(const float* __restrict__ hs, const float* __restrict__ l2,
                            const float* __restrict__ lam, short* __restrict__ fused)
{
    int idx = blockIdx.x * blockDim.x + threadIdx.x;
    int t = idx >> 9;
    float a0 = lam[t * 2 + 0], a1 = lam[t * 2 + 1];
    float4 a = ((const float4*)hs)[idx];
    float4 b = ((const float4*)l2)[idx];
    short o[4] = {f32_to_bf16(a0 * a.x + a1 * b.x), f32_to_bf16(a0 * a.y + a1 * b.y),
                  f32_to_bf16(a0 * a.z + a1 * b.z), f32_to_bf16(a0 * a.w + a1 * b.w)};
    *(uint2*)(fused + (size_t)idx * 4) = *(const uint2*)o;
}

// RoPE on q -> (H, T, HD) bf16, with 1/sqrt(HD) folded in.
__global__ void rope_q_kernel(const short* __restrict__ q, short* __restrict__ qr)
{
    int idx = blockIdx.x * blockDim.x + threadIdx.x;   // T*NH*64
    int d = idx & 63;
    int h = (idx >> 6) & 15;
    int t = idx >> 10;
    float fr = (float)t * __expf(-(float)d * 0.14391156831212787f);
    float s, c;
    sincosf(fr, &s, &c);
    const float sc = 0.08838834764831845f;  // 1/sqrt(128)
    const short* src = q + (size_t)t * D_MODEL + h * HD;
    float x1 = bf16_to_f32(src[d]) * sc, x2 = bf16_to_f32(src[d + 64]) * sc;
    short* dst = qr + ((size_t)h * T_SEQ + t) * HD;
    dst[d]      = f32_to_bf16(x1 * c - x2 * s);
    dst[d + 64] = f32_to_bf16(x2 * c + x1 * s);
}

// RoPE on k-half of kv (bf16 T x 1024) -> (KVH, T, HD) bf16.
__global__ void rope_k_kernel(const short* __restrict__ kv, short* __restrict__ kr)
{
    int idx = blockIdx.x * blockDim.x + threadIdx.x;   // T*NKVH*64
    int d = idx & 63;
    int kh = (idx >> 6) & 3;
    int t = idx >> 8;
    float fr = (float)t * __expf(-(float)d * 0.14391156831212787f);
    float s, c;
    sincosf(fr, &s, &c);
    const short* src = kv + (size_t)t * 1024 + kh * HD;
    float x1 = bf16_to_f32(src[d]), x2 = bf16_to_f32(src[d + 64]);
    short* dst = kr + ((size_t)kh * T_SEQ + t) * HD;
    dst[d]      = f32_to_bf16(x1 * c - x2 * s);
    dst[d + 64] = f32_to_bf16(x2 * c + x1 * s);
}

// ---------------------------------------------------------------------------
// Causal flash attention, max-free softmax, paired q-tiles for load balance.
// ---------------------------------------------------------------------------
__global__ __launch_bounds__(256, 1) void attn_kernel(
    const short* __restrict__ Qr, const short* __restrict__ Kr,
    const short* __restrict__ Vt, short* __restrict__ Out)
{
    const int pi = blockIdx.x;          // 0..15
    const int h = blockIdx.y;
    const int kvh = h >> 2;
    const int tid = threadIdx.x;
    const int wave = tid >> 6, lane = tid & 63;
    const int l16 = lane & 15, quad = lane >> 4;

    __shared__ short Klds[2][128 * 128];   // 64 KB, swizzled chunks
    __shared__ short Vlds[2][128 * 128];   // 64 KB, [hd][kv] swizzled
    __shared__ short Plds[4][16][136];     // 17 KB, padded (+8)

    const short* kbase = Kr + (size_t)kvh * T_SEQ * HD;
    const short* vbase = Vt + (size_t)kvh * HD * T_SEQ;

    for (int ph = 0; ph < 2; ++ph) {
        const int qt = ph ? (31 - pi) : pi;
        const int qbase = qt * 64 + wave * 16;
        const int n = (qt * 64 + 191) >> 7;     // ceil((qt+1)*64 / 128)

        bf16x8 qf[4];
        {
            const short* qrow = Qr + ((size_t)h * T_SEQ + qbase + l16) * HD;
            #pragma unroll
            for (int kc = 0; kc < 4; ++kc)
                qf[kc] = *(const bf16x8*)&qrow[kc * 32 + quad * 8];
        }
        f32x4 o[8] = {};
        float lsum[4] = {0.0f, 0.0f, 0.0f, 0.0f};

        __syncthreads();   // previous phase fully done with LDS

        {
            const short* ks = kbase;
            #pragma unroll
            for (int p = 0; p < 8; ++p) {
                int li = p * 256 + tid;
                int row = li >> 4, gs = (li & 15) ^ (row & 15);
                gl_to_lds16(ks + (size_t)row * HD + gs * 8,
                            &Klds[0][(size_t)(p * 256 + wave * 64) * 8]);
            }
            #pragma unroll
            for (int p = 0; p < 8; ++p) {
                int li = p * 256 + tid;
                int row = li >> 4, gs = (li & 15) ^ (row & 15);
                gl_to_lds16(vbase + (size_t)row * T_SEQ + gs * 8,
                            &Vlds[0][(size_t)(p * 256 + wave * 64) * 8]);
            }
        }

        for (int t = 0; t < n; ++t) {
            asm volatile("s_waitcnt vmcnt(0)\n\ts_barrier" ::: "memory");

            if (t + 1 < n) {   // prefetch next tile; overlaps compute below
                int kv1 = (t + 1) << 7;
                int nb = (t + 1) & 1;
                const short* ks = kbase + (size_t)kv1 * HD;
                #pragma unroll
                for (int p = 0; p < 8; ++p) {
                    int li = p * 256 + tid;
                    int row = li >> 4, gs = (li & 15) ^ (row & 15);
                    gl_to_lds16(ks + (size_t)row * HD + gs * 8,
                                &Klds[nb][(size_t)(p * 256 + wave * 64) * 8]);
                }
                #pragma unroll
                for (int p = 0; p < 8; ++p) {
                    int li = p * 256 + tid;
                    int row = li >> 4, gs = (li & 15) ^ (row & 15);
                    gl_to_lds16(vbase + (size_t)row * T_SEQ + kv1 + gs * 8,
                                &Vlds[nb][(size_t)(p * 256 + wave * 64) * 8]);
                }
            }

            const short* Kb = Klds[t & 1];
            const short* Vb = Vlds[t & 1];

            f32x4 s[8];
            #pragma unroll
            for (int ni = 0; ni < 8; ++ni) s[ni] = (f32x4){0, 0, 0, 0};
            #pragma unroll
            for (int ni = 0; ni < 8; ++ni)
                #pragma unroll
                for (int kc = 0; kc < 4; ++kc) {
                    bf16x8 b = *(const bf16x8*)
                        &Kb[(size_t)(ni * 16 + l16) * 128 + (((kc * 4 + quad) ^ l16) * 8)];
                    s[ni] = __builtin_amdgcn_mfma_f32_16x16x32_bf16(qf[kc], b, s[ni], 0, 0, 0);
                }

            if (t == n - 1) {
                int kvg0 = t << 7;
                #pragma unroll
                for (int ni = 0; ni < 8; ++ni) {
                    int kvg = kvg0 + ni * 16 + l16;
                    #pragma unroll
                    for (int r = 0; r < 4; ++r) {
                        int qg = qbase + quad * 4 + r;
                        float p = (kvg <= qg) ? __expf(s[ni][r]) : 0.0f;
                        lsum[r] += p;
                        Plds[wave][quad * 4 + r][ni * 16 + l16] = f32_to_bf16(p);
                    }
                }
            } else {
                #pragma unroll
                for (int ni = 0; ni < 8; ++ni)
                    #pragma unroll
                    for (int r = 0; r < 4; ++r) {
                        float p = __expf(s[ni][r]);
                        lsum[r] += p;
                        Plds[wave][quad * 4 + r][ni * 16 + l16] = f32_to_bf16(p);
                    }
            }
            asm volatile("s_waitcnt lgkmcnt(0)" ::: "memory");

            #pragma unroll
            for (int kc = 0; kc < 4; ++kc) {
                bf16x8 pa = *(const bf16x8*)&Plds[wave][l16][kc * 32 + quad * 8];
                #pragma unroll
                for (int d8 = 0; d8 < 8; ++d8) {
                    bf16x8 b = *(const bf16x8*)
                        &Vb[(size_t)(d8 * 16 + l16) * 128 + (((kc * 4 + quad) ^ l16) * 8)];
                    o[d8] = __builtin_amdgcn_mfma_f32_16x16x32_bf16(pa, b, o[d8], 0, 0, 0);
                }
            }
        }

        #pragma unroll
        for (int r = 0; r < 4; ++r) {
            #pragma unroll
            for (int off = 1; off < 16; off <<= 1)
                lsum[r] += __shfl_xor(lsum[r], off);
            lsum[r] = 1.0f / lsum[r];
        }
        #pragma unroll
        for (int d8 = 0; d8 < 8; ++d8)
            #pragma unroll
            for (int r = 0; r < 4; ++r) {
                int row = qbase + quad * 4 + r;
                Out[(size_t)row * D_MODEL + h * HD + d8 * 16 + l16] =
                    f32_to_bf16(o[d8][r] * lsum[r]);
            }
    }
}

// ---------------------------------------------------------------------------
extern "C" void kernel_launch(void* const* d_in, const int* in_sizes, int n_in,
                              void* d_out, int out_size, void* d_ws, size_t ws_size,
                              hipStream_t stream)
{
    const float* hs  = (const float*)d_in[0];
    const float* Wq  = (const float*)d_in[1];
    const float* Wk  = (const float*)d_in[2];
    const float* Wv  = (const float*)d_in[3];
    const float* Wo  = (const float*)d_in[4];
    const float* Wr1 = (const float*)d_in[5];
    const float* br1 = (const float*)d_in[6];
    const float* Wr2 = (const float*)d_in[7];
    const float* br2 = (const float*)d_in[8];
    float* out = (float*)d_out;

    char* w = (char*)d_ws;
    const size_t MB = 1u << 20;
    float* l2_f     = (float*)(w + 0 * MB);    // 16 MB
    short* hs_bf    = (short*)(w + 16 * MB);   // 8 MB (aliased as attn_bf later)
    short* Wq_t     = (short*)(w + 24 * MB);   // 8 MB
    short* Wkv_t    = (short*)(w + 32 * MB);   // 4 MB  [Wk^T | Wv^T]
    short* Wr1_t    = (short*)(w + 36 * MB);   // 4 MB
    short* Wo_t     = (short*)(w + 40 * MB);   // 8 MB
    short* q_bf     = (short*)(w + 48 * MB);   // 8 MB
    short* h_bf     = (short*)(w + 56 * MB);   // 4 MB
    short* fused_bf = (short*)(w + 60 * MB);   // 8 MB
    short* kv_bf    = (short*)(w + 68 * MB);   // 4 MB
    short* qr       = (short*)(w + 72 * MB);   // 8 MB (H,T,HD), pre-scaled
    short* kr       = (short*)(w + 80 * MB);   // 2 MB (KVH,T,HD)
    short* vr       = (short*)(w + 82 * MB);   // 2 MB (KVH,HD,T)
    float* lam_f    = (float*)(w + 84 * MB);   // 16 KB
    short* attn_bf  = hs_bf;                   // alias: hs_bf dead after q-gemm

    transpose_all_kernel<<<dim3(192, 64), 256, 0, stream>>>(
        Wq, Wk, Wv, Wr1, Wo, Wq_t, Wkv_t, Wr1_t, Wo_t);
    conv_bf16_kernel<<<(T_SEQ * D_MODEL / 4) / 256, 256, 0, stream>>>(hs, hs_bf);

    ema_kernel<<<dim3(T_SEQ / 128, D_MODEL / 256), 256, 0, stream>>>(hs, l2_f);

    gemm_bt_kernel<128><<<dim3(16, 16), 256, 0, stream>>>(
        hs_bf, Wq_t, nullptr, q_bf, 2048, 2048, 2048, nullptr, 0);

    gemm_bt_kernel<64><<<dim3(8, 32), 256, 0, stream>>>(
        q_bf, Wr1_t, nullptr, h_bf, 2048, 1024, 2048, br1, 1);

    lam_kernel<<<T_SEQ, 64, 0, stream>>>(h_bf, Wr2, br2, lam_f);

    fuse_kernel<<<(T_SEQ * D_MODEL / 4) / 256, 256, 0, stream>>>(hs, l2_f, lam_f, fused_bf);

    gemm_bt_kernel<64><<<dim3(8, 32), 256, 0, stream>>>(
        fused_bf, Wkv_t, nullptr, kv_bf, 2048, 1024, 2048, nullptr, 0);

    rope_q_kernel<<<(T_SEQ * NH * 64) / 256, 256, 0, stream>>>(q_bf, qr);
    rope_k_kernel<<<(T_SEQ * NKVH * 64) / 256, 256, 0, stream>>>(kv_bf, kr);
    transpose_bf_kernel<<<dim3(16, 64), 256, 0, stream>>>(kv_bf + 512, 1024, vr, 2048);

    attn_kernel<<<dim3(16, NH), 256, 0, stream>>>(qr, kr, vr, attn_bf);

    gemm_bt_kernel<128><<<dim3(16, 16), 256, 0, stream>>>(
        attn_bf, Wo_t, out, nullptr, 2048, 2048, 2048, nullptr, 0);
}